// Round 5
// baseline (213.750 us; speedup 1.0000x reference)
//
#include <hip/hip_runtime.h>
#include <hip/hip_bf16.h>
#include <stdint.h>

#define T_TOK 8192
#define D_IN  1024
#define N_EXP 8
#define D_OUT 1024

#define BM 128
#define BN 128
#define BK 32

typedef short s8v __attribute__((ext_vector_type(8)));
typedef float f4v __attribute__((ext_vector_type(4)));
typedef unsigned short ushort_t;

__device__ __forceinline__ ushort_t f2bf(float f) {
    uint32_t u = __float_as_uint(f);
    uint32_t r = (u + 0x7fffu + ((u >> 16) & 1u)) >> 16;
    return (ushort_t)r;
}

__device__ __forceinline__ float bf2f(ushort_t u) {
    return __uint_as_float(((uint32_t)u) << 16);
}

__device__ __forceinline__ void async_copy16(const void* g, void* lds) {
    __builtin_amdgcn_global_load_lds(
        (const __attribute__((address_space(1))) unsigned int*)g,
        (__attribute__((address_space(3))) unsigned int*)lds,
        16, 0, 0);
}

// Fenced pipeline barrier: memory clobber stops the compiler from moving any
// LDS/global op across it; lgkmcnt(0) guarantees own ds_reads completed
// before passing the barrier (inter-wave buffer-reuse safety).
#define PIPE_BARRIER_VM4() \
    asm volatile("s_waitcnt vmcnt(4) lgkmcnt(0)\n\ts_barrier" ::: "memory")
#define PIPE_BARRIER_VM0() \
    asm volatile("s_waitcnt vmcnt(0) lgkmcnt(0)\n\ts_barrier" ::: "memory")

// ------- cast: streaming f32 -> bf16 (32B/lane reads), zeroes cnt/psum -----
__global__ __launch_bounds__(256)
void cast_kernel(const float* __restrict__ x,
                 ushort_t* __restrict__ xb,
                 int* __restrict__ cnt,
                 float* __restrict__ psum) {
    size_t i = ((size_t)blockIdx.x * 256 + threadIdx.x) * 8;
    float4 v0 = *(const float4*)(x + i);
    float4 v1 = *(const float4*)(x + i + 4);
    s8v u;
    u[0] = (short)f2bf(v0.x); u[1] = (short)f2bf(v0.y);
    u[2] = (short)f2bf(v0.z); u[3] = (short)f2bf(v0.w);
    u[4] = (short)f2bf(v1.x); u[5] = (short)f2bf(v1.y);
    u[6] = (short)f2bf(v1.z); u[7] = (short)f2bf(v1.w);
    *(s8v*)(xb + i) = u;
    if (blockIdx.x == 0 && threadIdx.x < N_EXP) {
        cnt[threadIdx.x] = 0;
        psum[threadIdx.x] = 0.f;
    }
}

// ------- logits: LDS-tiled f32 GEMV [8192,1024]x[1024,8] -------------------
// 128 blocks x 64 tokens; x staged coalesced into LDS, Wr resident in LDS,
// 4 threads per token (256-d slices) + LDS tree reduce. f32 arithmetic
// throughout (routing tie-stability vs reference).
__global__ __launch_bounds__(256)
void logits_kernel(const float* __restrict__ x,
                   const float* __restrict__ Wr,
                   const float* __restrict__ br,
                   float* __restrict__ logits) {
    __shared__ float WrL[8192];        // [1024][8] f32 = 32 KB
    __shared__ float xt[64][69];       // staging / reduce scratch (17.7 KB)
    int tid = threadIdx.x;

#pragma unroll
    for (int it = 0; it < 8; ++it) {
        int o = (it * 256 + tid) * 4;
        *(float4*)(WrL + o) = *(const float4*)(Wr + o);
    }

    int t0 = blockIdx.x * 64;
    int tk = tid >> 2;          // token within block
    int q  = tid & 3;           // d-quarter

    float acc[N_EXP];
#pragma unroll
    for (int e = 0; e < N_EXP; ++e) acc[e] = 0.f;

    for (int kc = 0; kc < 16; ++kc) {          // 16 chunks of 64 d
        __syncthreads();                        // protect xt reuse
#pragma unroll
        for (int it = 0; it < 4; ++it) {
            int lin = it * 256 + tid;           // 0..1023
            int r   = lin >> 4;                 // token row
            int c4  = (lin & 15) * 4;           // d offset
            *(float4*)(&xt[r][c4]) =
                *(const float4*)(x + (size_t)(t0 + r) * D_IN + kc * 64 + c4);
        }
        __syncthreads();
#pragma unroll
        for (int j = 0; j < 16; ++j) {
            int dloc = q * 16 + j;
            float xv = xt[tk][dloc];
            const float* wr = WrL + (size_t)(kc * 64 + dloc) * 8;
            float4 w0 = *(const float4*)(wr);
            float4 w1 = *(const float4*)(wr + 4);
            acc[0] += xv * w0.x; acc[1] += xv * w0.y;
            acc[2] += xv * w0.z; acc[3] += xv * w0.w;
            acc[4] += xv * w1.x; acc[5] += xv * w1.y;
            acc[6] += xv * w1.z; acc[7] += xv * w1.w;
        }
    }

    // 4-way reduce per token via LDS (reuse xt: 64*36 floats needed)
    __syncthreads();
    float* rp = (float*)xt;
#pragma unroll
    for (int e = 0; e < N_EXP; ++e) rp[tk * 36 + q * 8 + e] = acc[e];
    __syncthreads();
    if (q == 0) {
#pragma unroll
        for (int e = 0; e < N_EXP; ++e) {
            float s = rp[tk * 36 + e] + rp[tk * 36 + 8 + e] +
                      rp[tk * 36 + 16 + e] + rp[tk * 36 + 24 + e];
            logits[(size_t)(t0 + tk) * N_EXP + e] = s + br[e];
        }
    }
}

// ------- We transpose: [E,D,DOUT] f32 -> [E,DOUT,D] bf16 (64x64 LDS tiles) -
__global__ __launch_bounds__(256)
void wetrans_kernel(const float* __restrict__ We,
                    ushort_t* __restrict__ Webt) {
    __shared__ float tile[64][65];
    int b  = blockIdx.x;           // 0..2047
    int e  = b >> 8;
    int k0 = ((b >> 4) & 15) * 64; // D index
    int h0 = (b & 15) * 64;        // DOUT index
    int tid = threadIdx.x;

    const float* src = We + ((size_t)e * D_IN + k0) * D_OUT + h0;
#pragma unroll
    for (int it = 0; it < 4; ++it) {
        int lin = it * 256 + tid;
        int r = lin >> 4;
        int c4 = (lin & 15) * 4;
        float4 v = *(const float4*)(src + (size_t)r * D_OUT + c4);
        tile[r][c4]     = v.x; tile[r][c4 + 1] = v.y;
        tile[r][c4 + 2] = v.z; tile[r][c4 + 3] = v.w;
    }
    __syncthreads();
    ushort_t* dst = Webt + ((size_t)e * D_OUT + h0) * D_IN + k0;
#pragma unroll
    for (int it = 0; it < 4; ++it) {
        int lin = it * 256 + tid;
        int h = lin >> 4;
        int k4 = (lin & 15) * 4;
        ushort4 u;
        u.x = f2bf(tile[k4][h]);     u.y = f2bf(tile[k4 + 1][h]);
        u.z = f2bf(tile[k4 + 2][h]); u.w = f2bf(tile[k4 + 3][h]);
        *(ushort4*)(dst + (size_t)h * D_IN + k4) = u;
    }
}

// ------- route: softmax + top2 + expert lists (1 token per thread) ----------
__global__ __launch_bounds__(256)
void route_kernel(const float* __restrict__ logits,
                  float* __restrict__ wslot,
                  int* __restrict__ entries,
                  int* __restrict__ cnt,
                  float* __restrict__ psum) {
    __shared__ int lcnt[N_EXP];
    __shared__ int gbase[N_EXP];
    __shared__ float lps[N_EXP];
    int tid  = threadIdx.x;
    int lane = tid & 63;
    int t    = blockIdx.x * 256 + tid;
    if (tid < N_EXP) { lcnt[tid] = 0; lps[tid] = 0.f; }
    __syncthreads();

    float p[N_EXP];
    float4 l0 = *(const float4*)(logits + (size_t)t * N_EXP);
    float4 l1 = *(const float4*)(logits + (size_t)t * N_EXP + 4);
    p[0] = l0.x; p[1] = l0.y; p[2] = l0.z; p[3] = l0.w;
    p[4] = l1.x; p[5] = l1.y; p[6] = l1.z; p[7] = l1.w;

    float m = p[0];
#pragma unroll
    for (int e = 1; e < N_EXP; ++e) m = fmaxf(m, p[e]);
    float Z = 0.f;
#pragma unroll
    for (int e = 0; e < N_EXP; ++e) { p[e] = expf(p[e] - m); Z += p[e]; }
    float invZ = 1.f / Z;
#pragma unroll
    for (int e = 0; e < N_EXP; ++e) p[e] *= invZ;

#pragma unroll
    for (int e = 0; e < N_EXP; ++e) {
        float v = p[e];
#pragma unroll
        for (int off = 32; off; off >>= 1) v += __shfl_xor(v, off, 64);
        if (lane == 0) atomicAdd(&lps[e], v);
    }

    int i0 = 0; float b0 = p[0];
#pragma unroll
    for (int e = 1; e < N_EXP; ++e) if (p[e] > b0) { b0 = p[e]; i0 = e; }
    int i1 = (i0 == 0) ? 1 : 0; float b1 = p[i1];
#pragma unroll
    for (int e = 0; e < N_EXP; ++e)
        if (e != i0 && p[e] > b1) { b1 = p[e]; i1 = e; }
    float denom = b0 + b1 + 1e-9f;
    float2 w01; w01.x = b0 / denom; w01.y = b1 / denom;
    *(float2*)(wslot + 2 * t) = w01;

    int lpos0 = atomicAdd(&lcnt[i0], 1);
    int lpos1 = atomicAdd(&lcnt[i1], 1);
    __syncthreads();
    if (tid < N_EXP) {
        gbase[tid] = atomicAdd(&cnt[tid], lcnt[tid]);
        atomicAdd(&psum[tid], lps[tid]);
    }
    __syncthreads();
    entries[i0 * T_TOK + gbase[i0] + lpos0] = 2 * t;
    entries[i1 * T_TOK + gbase[i1] + lpos1] = 2 * t + 1;
}

// ------- grouped GEMM, 128x128, 3-deep LDS pipeline with FENCED
//         s_waitcnt vmcnt(4)+s_barrier (never full drain), XOR swizzle,
//         XCD affinity, LDS-staged coalesced bf16 epilogue ------------------
__global__ __launch_bounds__(256, 3)
void moe_gemm(const ushort_t* __restrict__ xb,
              const ushort_t* __restrict__ Webt,
              const float* __restrict__ be,
              const int* __restrict__ entries,
              const int* __restrict__ cnt,
              const float* __restrict__ wslot,
              ushort_t* __restrict__ yslot) {
    int idx  = blockIdx.x;
    int e    = idx & 7;          // XCD-affinity: round-robin block->XCD
    int rest = idx >> 3;
    int bn   = rest & 7;
    int bm   = rest >> 3;
    int cnte = cnt[e];
    if (bm * BM >= cnte) return;

    // 3 pipeline buffers x (As 8KB + Bs 8KB) = 48 KB; epilogue tile aliases
    __shared__ __attribute__((aligned(16))) char smem[3 * 16384];

    int tid    = threadIdx.x;
    int lane   = tid & 63;
    int wv     = tid >> 6;
    int lane15 = lane & 15;
    int quad   = lane >> 4;
    int wm = (wv >> 1) * 64;
    int wn = (wv & 1) * 64;

    // staging addresses (chunk XOR-swizzle to kill LDS read conflicts)
    int rA   = tid >> 2;
    int cper = (tid & 3) ^ ((rA >> 1) & 3);
    const int* epe = entries + e * T_TOK;
    int r0 = bm * BM + rA;
    int r1 = r0 + 64;
    int c0 = r0 < cnte ? r0 : cnte - 1;
    int c1 = r1 < cnte ? r1 : cnte - 1;
    int tok0 = epe[c0] >> 1;
    int tok1 = epe[c1] >> 1;
    const ushort_t* gA0 = xb + (size_t)tok0 * D_IN + cper * 8;
    const ushort_t* gA1 = xb + (size_t)tok1 * D_IN + cper * 8;
    const ushort_t* WB  = Webt + (size_t)e * D_IN * D_OUT + cper * 8;
    const ushort_t* gB0 = WB + (size_t)(bn * BN + rA) * D_IN;
    const ushort_t* gB1 = WB + (size_t)(bn * BN + rA + 64) * D_IN;
    int ldsOff = wv * 1024;

    // fragment read offsets (mirror the XOR swizzle)
    int aoff[4], boff[4];
#pragma unroll
    for (int mi = 0; mi < 4; ++mi) {
        int m = wm + mi * 16 + lane15;
        aoff[mi] = m * 64 + (quad ^ ((m >> 1) & 3)) * 16;
        int n = wn + mi * 16 + lane15;
        boff[mi] = n * 64 + (quad ^ ((n >> 1) & 3)) * 16;
    }

    f4v acc[4][4];
#pragma unroll
    for (int mi = 0; mi < 4; ++mi)
#pragma unroll
        for (int ni = 0; ni < 4; ++ni)
            acc[mi][ni] = (f4v){0.f, 0.f, 0.f, 0.f};

#define STAGE(ti)                                                          \
    do {                                                                   \
        char* _b = smem + ((ti) % 3) * 16384;                              \
        int _k = (ti) * BK;                                                \
        async_copy16(gA0 + _k, _b + ldsOff);                               \
        async_copy16(gA1 + _k, _b + 4096 + ldsOff);                        \
        async_copy16(gB0 + _k, _b + 8192 + ldsOff);                        \
        async_copy16(gB1 + _k, _b + 12288 + ldsOff);                       \
    } while (0)

#define COMPUTE(ti)                                                        \
    do {                                                                   \
        const char* ab = smem + ((ti) % 3) * 16384;                        \
        const char* bb = ab + 8192;                                        \
        s8v a[4], b[4];                                                    \
        _Pragma("unroll")                                                  \
        for (int mi = 0; mi < 4; ++mi) a[mi] = *(const s8v*)(ab + aoff[mi]); \
        _Pragma("unroll")                                                  \
        for (int ni = 0; ni < 4; ++ni) b[ni] = *(const s8v*)(bb + boff[ni]); \
        _Pragma("unroll")                                                  \
        for (int mi = 0; mi < 4; ++mi)                                     \
            _Pragma("unroll")                                              \
            for (int ni = 0; ni < 4; ++ni)                                 \
                acc[mi][ni] = __builtin_amdgcn_mfma_f32_16x16x32_bf16(     \
                    a[mi], b[ni], acc[mi][ni], 0, 0, 0);                   \
    } while (0)

    // prologue: tiles 0 and 1 in flight
    STAGE(0);
    STAGE(1);

    // main loop: wait for tile i (keep tile i+1's 4 loads in flight),
    // prefetch tile i+2, compute tile i.  NT = 1024/32 = 32 tiles.
    for (int i = 0; i < 30; ++i) {
        PIPE_BARRIER_VM4();
        STAGE(i + 2);
        COMPUTE(i);
    }
    PIPE_BARRIER_VM4();   // tile 30 ready (31 still in flight)
    COMPUTE(30);
    PIPE_BARRIER_VM0();   // tile 31 ready
    COMPUTE(31);

    // ---- epilogue: scale+bias, stage tile in LDS (aliased), coalesced store
    __syncthreads();   // all ds_reads done before smem is reused as ot
    ushort_t (*ot)[136] = (ushort_t(*)[136])smem;

#pragma unroll
    for (int mi = 0; mi < 4; ++mi) {
#pragma unroll
        for (int r = 0; r < 4; ++r) {
            int lrow = wm + mi * 16 + quad * 4 + r;
            int grow = bm * BM + lrow;
            int cr   = grow < cnte ? grow : cnte - 1;
            float w  = grow < cnte ? wslot[epe[cr]] : 0.f;
#pragma unroll
            for (int ni = 0; ni < 4; ++ni) {
                int lcol = wn + ni * 16 + lane15;
                float bev = be[e * D_OUT + bn * BN + lcol];
                ot[lrow][lcol] = f2bf(w * (acc[mi][ni][r] + bev));
            }
        }
    }
    __syncthreads();

    int row  = tid >> 1;
    int half = tid & 1;
    int grow = bm * BM + row;
    if (grow < cnte) {
        int ent = epe[grow];
        ushort_t* dst = yslot + (size_t)ent * D_OUT + bn * BN + half * 64;
        const ushort_t* srcr = &ot[row][half * 64];
#pragma unroll
        for (int j = 0; j < 8; ++j)
            *(s8v*)(dst + j * 8) = *(const s8v*)(srcr + j * 8);
    }
}

// ------- combine (+ fused aux): y[t] = ys[2t] + ys[2t+1], 8 floats/thread ---
__global__ __launch_bounds__(256)
void combine_kernel(const ushort_t* __restrict__ yslot,
                    const float* __restrict__ psum,
                    const int* __restrict__ cnt,
                    float* __restrict__ out) {
    size_t i = ((size_t)blockIdx.x * 256 + threadIdx.x) * 8;
    size_t t = i >> 10;
    size_t h = i & 1023;
    const ushort_t* p0 = yslot + (2 * t) * D_OUT + h;
    s8v a = *(const s8v*)p0;
    s8v b = *(const s8v*)(p0 + D_OUT);
    float4 o0, o1;
    o0.x = bf2f((ushort_t)a[0]) + bf2f((ushort_t)b[0]);
    o0.y = bf2f((ushort_t)a[1]) + bf2f((ushort_t)b[1]);
    o0.z = bf2f((ushort_t)a[2]) + bf2f((ushort_t)b[2]);
    o0.w = bf2f((ushort_t)a[3]) + bf2f((ushort_t)b[3]);
    o1.x = bf2f((ushort_t)a[4]) + bf2f((ushort_t)b[4]);
    o1.y = bf2f((ushort_t)a[5]) + bf2f((ushort_t)b[5]);
    o1.z = bf2f((ushort_t)a[6]) + bf2f((ushort_t)b[6]);
    o1.w = bf2f((ushort_t)a[7]) + bf2f((ushort_t)b[7]);
    *(float4*)(out + i) = o0;
    *(float4*)(out + i + 4) = o1;
    if (i == 0) {
        float s = 0.f;
#pragma unroll
        for (int e = 0; e < N_EXP; ++e)
            s += (psum[e] / (float)T_TOK) * ((float)cnt[e] / (float)(T_TOK * 2));
        out[(size_t)T_TOK * D_OUT] = (float)N_EXP * s;
    }
}

extern "C" void kernel_launch(void* const* d_in, const int* in_sizes, int n_in,
                              void* d_out, int out_size, void* d_ws, size_t ws_size,
                              hipStream_t stream) {
    const float* x  = (const float*)d_in[0];
    const float* Wr = (const float*)d_in[1];
    const float* br = (const float*)d_in[2];
    const float* We = (const float*)d_in[3];
    const float* be = (const float*)d_in[4];
    float* out = (float*)d_out;

    char* ws = (char*)d_ws;
    ushort_t* xb      = (ushort_t*)(ws);                    // 16 MiB
    ushort_t* Webt    = (ushort_t*)(ws + 16777216);         // 16 MiB
    ushort_t* yslot   = (ushort_t*)(ws + 33554432);         // 32 MiB (bf16)
    int*      entries = (int*)(ws + 67108864);              // 256 KiB
    float*    wslot   = (float*)(ws + 67371008);            // 64 KiB
    float*    logits  = (float*)(ws + 67436544);            // 256 KiB
    float*    psum    = (float*)(ws + 67698688);            // 32 B
    int*      cnt     = (int*)(ws + 67698720);              // 32 B

    hipLaunchKernelGGL(cast_kernel, dim3(4096), dim3(256), 0, stream,
                       x, xb, cnt, psum);
    hipLaunchKernelGGL(logits_kernel, dim3(128), dim3(256), 0, stream,
                       x, Wr, br, logits);
    hipLaunchKernelGGL(wetrans_kernel, dim3(2048), dim3(256), 0, stream,
                       We, Webt);
    hipLaunchKernelGGL(route_kernel, dim3(32), dim3(256), 0, stream,
                       logits, wslot, entries, cnt, psum);
    hipLaunchKernelGGL(moe_gemm, dim3(4096), dim3(256), 0, stream,
                       xb, Webt, be, entries, cnt, wslot, yslot);
    hipLaunchKernelGGL(combine_kernel, dim3(4096), dim3(256), 0, stream,
                       yslot, psum, cnt, out);
}

// Round 7
// 195.272 us; speedup vs baseline: 1.0946x; 1.0946x over previous
//
#include <hip/hip_runtime.h>
#include <hip/hip_bf16.h>
#include <stdint.h>

#define T_TOK 8192
#define D_IN  1024
#define N_EXP 8
#define D_OUT 1024

#define BM 128
#define BN 128
#define BK 32

typedef short s8v __attribute__((ext_vector_type(8)));
typedef float f4v __attribute__((ext_vector_type(4)));
typedef unsigned short ushort_t;

__device__ __forceinline__ ushort_t f2bf(float f) {
    uint32_t u = __float_as_uint(f);
    uint32_t r = (u + 0x7fffu + ((u >> 16) & 1u)) >> 16;
    return (ushort_t)r;
}

__device__ __forceinline__ float bf2f(ushort_t u) {
    return __uint_as_float(((uint32_t)u) << 16);
}

__device__ __forceinline__ void async_copy16(const void* g, void* lds) {
    __builtin_amdgcn_global_load_lds(
        (const __attribute__((address_space(1))) unsigned int*)g,
        (__attribute__((address_space(3))) unsigned int*)lds,
        16, 0, 0);
}

// Fenced pipeline barrier: memory clobber stops the compiler from moving any
// LDS/global op across it; lgkmcnt(0) guarantees own ds_reads completed
// before passing the barrier (inter-wave buffer-reuse safety).
#define PIPE_BARRIER_VM4() \
    asm volatile("s_waitcnt vmcnt(4) lgkmcnt(0)\n\ts_barrier" ::: "memory")
#define PIPE_BARRIER_VM0() \
    asm volatile("s_waitcnt vmcnt(0) lgkmcnt(0)\n\ts_barrier" ::: "memory")

// ------- prep_all: mixed grid, co-dispatched for CU overlap ----------------
//   blocks [0,512):   16 tokens each — x-cast + f32 logits GEMV (Wr^T in
//                     LDS, conflict-free broadcast reads) + softmax + top2
//                     + expert-list build (route fused, logits never hit HBM)
//   blocks [512,2560): We transpose/cast 64x64 tiles (f32 -> bf16 B^T)
// cnt/psum must be zeroed before launch (64B memset).
#define WRT_STRIDE 1028           // 1028 % 32 == 4: expert e -> bank-quad 4e
__global__ __launch_bounds__(256)
void prep_all(const float* __restrict__ x,
              const float* __restrict__ Wr,
              const float* __restrict__ br,
              const float* __restrict__ We,
              ushort_t* __restrict__ xb,
              ushort_t* __restrict__ Webt,
              float* __restrict__ wslot,
              int* __restrict__ entries,
              int* __restrict__ cnt,
              float* __restrict__ psum) {
    // union'd LDS:
    //  token branch: WrT 8x1028 f32 (32896B) | xt 16x132 f32 (8448B) | lg 16x9
    //  wetrans branch: tile[64][65] f32 (16640B)
    __shared__ __attribute__((aligned(16))) char shbuf[41920];
    __shared__ int   lcnt[N_EXP];
    __shared__ int   gbase[N_EXP];
    __shared__ float lps[N_EXP];

    int bid = blockIdx.x;
    int tid = threadIdx.x;

    if (bid < 512) {
        float* WrT = (float*)shbuf;                       // [8][1028]
        float (*xt)[132] = (float(*)[132])(shbuf + 32896); // [16][132]
        float (*lg)[9]   = (float(*)[9])(shbuf + 41344);   // [16][9]
        if (tid < N_EXP) { lcnt[tid] = 0; lps[tid] = 0.f; }

        // stage Wr transposed: Wr[d][e] -> WrT[e][d]
#pragma unroll
        for (int it = 0; it < 8; ++it) {
            int o = (it * 256 + tid) * 4;     // linear over [1024][8]
            float4 v = *(const float4*)(Wr + o);
            int d0 = o >> 3, e0 = o & 7;      // e0 in {0,4}
            WrT[(e0 + 0) * WRT_STRIDE + d0] = v.x;
            WrT[(e0 + 1) * WRT_STRIDE + d0] = v.y;
            WrT[(e0 + 2) * WRT_STRIDE + d0] = v.z;
            WrT[(e0 + 3) * WRT_STRIDE + d0] = v.w;
        }

        int t0 = bid * 16;
        int tk = tid >> 4;          // token 0..15
        int e  = (tid >> 1) & 7;    // expert
        int h  = tid & 1;           // d-half of each 128-chunk

        f4v a4 = (f4v){0.f, 0.f, 0.f, 0.f};
        for (int kc = 0; kc < 8; ++kc) {      // 8 chunks of 128 d
            __syncthreads();                  // protect xt reuse
#pragma unroll
            for (int it = 0; it < 2; ++it) {
                int lin = it * 256 + tid;     // 0..511 over 16x128
                int r   = lin >> 5;
                int c4  = (lin & 31) * 4;
                float4 v = *(const float4*)(
                    x + (size_t)(t0 + r) * D_IN + kc * 128 + c4);
                ushort4 u;
                u.x = f2bf(v.x); u.y = f2bf(v.y);
                u.z = f2bf(v.z); u.w = f2bf(v.w);
                *(ushort4*)(xb + (size_t)(t0 + r) * D_IN + kc * 128 + c4) = u;
                *(float4*)(&xt[r][c4]) = v;
            }
            __syncthreads();
            const float* xrow = &xt[tk][h * 64];
            const float* wrow = WrT + e * WRT_STRIDE + kc * 128 + h * 64;
#pragma unroll
            for (int g = 0; g < 16; ++g) {
                float4 xv = *(const float4*)(xrow + g * 4);
                float4 wv = *(const float4*)(wrow + g * 4);
                a4[0] += xv.x * wv.x; a4[1] += xv.y * wv.y;
                a4[2] += xv.z * wv.z; a4[3] += xv.w * wv.w;
            }
        }
        float accs = (a4[0] + a4[1]) + (a4[2] + a4[3]);
        accs += __shfl_xor(accs, 1, 64);      // combine the two d-halves
        if (h == 0) lg[tk][e] = accs;
        __syncthreads();

        // routing tail: one thread per token (16 lanes of wave 0)
        int i0 = 0, i1 = 1, lpos0 = 0, lpos1 = 0;
        if (tid < 16) {
            int t = t0 + tid;
            float p[N_EXP];
#pragma unroll
            for (int ee = 0; ee < N_EXP; ++ee) p[ee] = lg[tid][ee] + br[ee];
            float m = p[0];
#pragma unroll
            for (int ee = 1; ee < N_EXP; ++ee) m = fmaxf(m, p[ee]);
            float Z = 0.f;
#pragma unroll
            for (int ee = 0; ee < N_EXP; ++ee) { p[ee] = expf(p[ee] - m); Z += p[ee]; }
            float invZ = 1.f / Z;
#pragma unroll
            for (int ee = 0; ee < N_EXP; ++ee) p[ee] *= invZ;

            float b0 = p[0];
#pragma unroll
            for (int ee = 1; ee < N_EXP; ++ee) if (p[ee] > b0) { b0 = p[ee]; i0 = ee; }
            i1 = (i0 == 0) ? 1 : 0; float b1 = p[i1];
#pragma unroll
            for (int ee = 0; ee < N_EXP; ++ee)
                if (ee != i0 && p[ee] > b1) { b1 = p[ee]; i1 = ee; }
            float denom = b0 + b1 + 1e-9f;
            float2 w01; w01.x = b0 / denom; w01.y = b1 / denom;
            *(float2*)(wslot + 2 * t) = w01;
#pragma unroll
            for (int ee = 0; ee < N_EXP; ++ee) atomicAdd(&lps[ee], p[ee]);
            lpos0 = atomicAdd(&lcnt[i0], 1);
            lpos1 = atomicAdd(&lcnt[i1], 1);
        }
        __syncthreads();
        if (tid < N_EXP) {
            gbase[tid] = atomicAdd(&cnt[tid], lcnt[tid]);
            atomicAdd(&psum[tid], lps[tid]);
        }
        __syncthreads();
        if (tid < 16) {
            int t = t0 + tid;
            entries[i0 * T_TOK + gbase[i0] + lpos0] = 2 * t;
            entries[i1 * T_TOK + gbase[i1] + lpos1] = 2 * t + 1;
        }
    } else {
        float (*tile)[65] = (float(*)[65])shbuf;
        int b  = bid - 512;            // 0..2047
        int e  = b >> 8;
        int k0 = ((b >> 4) & 15) * 64; // D index
        int h0 = (b & 15) * 64;        // DOUT index

        const float* src = We + ((size_t)e * D_IN + k0) * D_OUT + h0;
#pragma unroll
        for (int it = 0; it < 4; ++it) {
            int lin = it * 256 + tid;
            int r = lin >> 4;
            int c4 = (lin & 15) * 4;
            float4 v = *(const float4*)(src + (size_t)r * D_OUT + c4);
            tile[r][c4]     = v.x; tile[r][c4 + 1] = v.y;
            tile[r][c4 + 2] = v.z; tile[r][c4 + 3] = v.w;
        }
        __syncthreads();
        ushort_t* dst = Webt + ((size_t)e * D_OUT + h0) * D_IN + k0;
#pragma unroll
        for (int it = 0; it < 4; ++it) {
            int lin = it * 256 + tid;
            int h = lin >> 4;
            int k4 = (lin & 15) * 4;
            ushort4 u;
            u.x = f2bf(tile[k4][h]);     u.y = f2bf(tile[k4 + 1][h]);
            u.z = f2bf(tile[k4 + 2][h]); u.w = f2bf(tile[k4 + 3][h]);
            *(ushort4*)(dst + (size_t)h * D_IN + k4) = u;
        }
    }
}

// ------- grouped GEMM, 128x128, 3-deep LDS pipeline with FENCED
//         s_waitcnt vmcnt(4)+s_barrier (never full drain), XOR swizzle,
//         XCD affinity, LDS-staged coalesced bf16 epilogue ------------------
__global__ __launch_bounds__(256, 3)
void moe_gemm(const ushort_t* __restrict__ xb,
              const ushort_t* __restrict__ Webt,
              const float* __restrict__ be,
              const int* __restrict__ entries,
              const int* __restrict__ cnt,
              const float* __restrict__ wslot,
              ushort_t* __restrict__ yslot) {
    int idx  = blockIdx.x;
    int e    = idx & 7;          // XCD-affinity: round-robin block->XCD
    int rest = idx >> 3;
    int bn   = rest & 7;
    int bm   = rest >> 3;
    int cnte = cnt[e];
    if (bm * BM >= cnte) return;

    // 3 pipeline buffers x (As 8KB + Bs 8KB) = 48 KB; epilogue tile aliases
    __shared__ __attribute__((aligned(16))) char smem[3 * 16384];

    int tid    = threadIdx.x;
    int lane   = tid & 63;
    int wv     = tid >> 6;
    int lane15 = lane & 15;
    int quad   = lane >> 4;
    int wm = (wv >> 1) * 64;
    int wn = (wv & 1) * 64;

    // staging addresses (chunk XOR-swizzle to kill LDS read conflicts)
    int rA   = tid >> 2;
    int cper = (tid & 3) ^ ((rA >> 1) & 3);
    const int* epe = entries + e * T_TOK;
    int r0 = bm * BM + rA;
    int r1 = r0 + 64;
    int c0 = r0 < cnte ? r0 : cnte - 1;
    int c1 = r1 < cnte ? r1 : cnte - 1;
    int tok0 = epe[c0] >> 1;
    int tok1 = epe[c1] >> 1;
    const ushort_t* gA0 = xb + (size_t)tok0 * D_IN + cper * 8;
    const ushort_t* gA1 = xb + (size_t)tok1 * D_IN + cper * 8;
    const ushort_t* WB  = Webt + (size_t)e * D_IN * D_OUT + cper * 8;
    const ushort_t* gB0 = WB + (size_t)(bn * BN + rA) * D_IN;
    const ushort_t* gB1 = WB + (size_t)(bn * BN + rA + 64) * D_IN;
    int ldsOff = wv * 1024;

    // fragment read offsets (mirror the XOR swizzle)
    int aoff[4], boff[4];
#pragma unroll
    for (int mi = 0; mi < 4; ++mi) {
        int m = wm + mi * 16 + lane15;
        aoff[mi] = m * 64 + (quad ^ ((m >> 1) & 3)) * 16;
        int n = wn + mi * 16 + lane15;
        boff[mi] = n * 64 + (quad ^ ((n >> 1) & 3)) * 16;
    }

    f4v acc[4][4];
#pragma unroll
    for (int mi = 0; mi < 4; ++mi)
#pragma unroll
        for (int ni = 0; ni < 4; ++ni)
            acc[mi][ni] = (f4v){0.f, 0.f, 0.f, 0.f};

#define STAGE(ti)                                                          \
    do {                                                                   \
        char* _b = smem + ((ti) % 3) * 16384;                              \
        int _k = (ti) * BK;                                                \
        async_copy16(gA0 + _k, _b + ldsOff);                               \
        async_copy16(gA1 + _k, _b + 4096 + ldsOff);                        \
        async_copy16(gB0 + _k, _b + 8192 + ldsOff);                        \
        async_copy16(gB1 + _k, _b + 12288 + ldsOff);                       \
    } while (0)

#define COMPUTE(ti)                                                        \
    do {                                                                   \
        const char* ab = smem + ((ti) % 3) * 16384;                        \
        const char* bb = ab + 8192;                                        \
        s8v a[4], b[4];                                                    \
        _Pragma("unroll")                                                  \
        for (int mi = 0; mi < 4; ++mi) a[mi] = *(const s8v*)(ab + aoff[mi]); \
        _Pragma("unroll")                                                  \
        for (int ni = 0; ni < 4; ++ni) b[ni] = *(const s8v*)(bb + boff[ni]); \
        _Pragma("unroll")                                                  \
        for (int mi = 0; mi < 4; ++mi)                                     \
            _Pragma("unroll")                                              \
            for (int ni = 0; ni < 4; ++ni)                                 \
                acc[mi][ni] = __builtin_amdgcn_mfma_f32_16x16x32_bf16(     \
                    a[mi], b[ni], acc[mi][ni], 0, 0, 0);                   \
    } while (0)

    // prologue: tiles 0 and 1 in flight
    STAGE(0);
    STAGE(1);

    // main loop: wait for tile i (keep tile i+1's 4 loads in flight),
    // prefetch tile i+2, compute tile i.  NT = 1024/32 = 32 tiles.
    for (int i = 0; i < 30; ++i) {
        PIPE_BARRIER_VM4();
        STAGE(i + 2);
        COMPUTE(i);
    }
    PIPE_BARRIER_VM4();   // tile 30 ready (31 still in flight)
    COMPUTE(30);
    PIPE_BARRIER_VM0();   // tile 31 ready
    COMPUTE(31);

    // ---- epilogue: scale+bias, stage tile in LDS (aliased), coalesced store
    __syncthreads();   // all ds_reads done before smem is reused as ot
    ushort_t (*ot)[136] = (ushort_t(*)[136])smem;

#pragma unroll
    for (int mi = 0; mi < 4; ++mi) {
#pragma unroll
        for (int r = 0; r < 4; ++r) {
            int lrow = wm + mi * 16 + quad * 4 + r;
            int grow = bm * BM + lrow;
            int cr   = grow < cnte ? grow : cnte - 1;
            float w  = grow < cnte ? wslot[epe[cr]] : 0.f;
#pragma unroll
            for (int ni = 0; ni < 4; ++ni) {
                int lcol = wn + ni * 16 + lane15;
                float bev = be[e * D_OUT + bn * BN + lcol];
                ot[lrow][lcol] = f2bf(w * (acc[mi][ni][r] + bev));
            }
        }
    }
    __syncthreads();

    int row  = tid >> 1;
    int half = tid & 1;
    int grow = bm * BM + row;
    if (grow < cnte) {
        int ent = epe[grow];
        ushort_t* dst = yslot + (size_t)ent * D_OUT + bn * BN + half * 64;
        const ushort_t* srcr = &ot[row][half * 64];
#pragma unroll
        for (int j = 0; j < 8; ++j)
            *(s8v*)(dst + j * 8) = *(const s8v*)(srcr + j * 8);
    }
}

// ------- combine (+ fused aux): y[t] = ys[2t] + ys[2t+1], 8 floats/thread ---
__global__ __launch_bounds__(256)
void combine_kernel(const ushort_t* __restrict__ yslot,
                    const float* __restrict__ psum,
                    const int* __restrict__ cnt,
                    float* __restrict__ out) {
    size_t i = ((size_t)blockIdx.x * 256 + threadIdx.x) * 8;
    size_t t = i >> 10;
    size_t h = i & 1023;
    const ushort_t* p0 = yslot + (2 * t) * D_OUT + h;
    s8v a = *(const s8v*)p0;
    s8v b = *(const s8v*)(p0 + D_OUT);
    float4 o0, o1;
    o0.x = bf2f((ushort_t)a[0]) + bf2f((ushort_t)b[0]);
    o0.y = bf2f((ushort_t)a[1]) + bf2f((ushort_t)b[1]);
    o0.z = bf2f((ushort_t)a[2]) + bf2f((ushort_t)b[2]);
    o0.w = bf2f((ushort_t)a[3]) + bf2f((ushort_t)b[3]);
    o1.x = bf2f((ushort_t)a[4]) + bf2f((ushort_t)b[4]);
    o1.y = bf2f((ushort_t)a[5]) + bf2f((ushort_t)b[5]);
    o1.z = bf2f((ushort_t)a[6]) + bf2f((ushort_t)b[6]);
    o1.w = bf2f((ushort_t)a[7]) + bf2f((ushort_t)b[7]);
    *(float4*)(out + i) = o0;
    *(float4*)(out + i + 4) = o1;
    if (i == 0) {
        float s = 0.f;
#pragma unroll
        for (int e = 0; e < N_EXP; ++e)
            s += (psum[e] / (float)T_TOK) * ((float)cnt[e] / (float)(T_TOK * 2));
        out[(size_t)T_TOK * D_OUT] = (float)N_EXP * s;
    }
}

extern "C" void kernel_launch(void* const* d_in, const int* in_sizes, int n_in,
                              void* d_out, int out_size, void* d_ws, size_t ws_size,
                              hipStream_t stream) {
    const float* x  = (const float*)d_in[0];
    const float* Wr = (const float*)d_in[1];
    const float* br = (const float*)d_in[2];
    const float* We = (const float*)d_in[3];
    const float* be = (const float*)d_in[4];
    float* out = (float*)d_out;

    char* ws = (char*)d_ws;
    ushort_t* xb      = (ushort_t*)(ws);                    // 16 MiB
    ushort_t* Webt    = (ushort_t*)(ws + 16777216);         // 16 MiB
    ushort_t* yslot   = (ushort_t*)(ws + 33554432);         // 32 MiB (bf16)
    int*      entries = (int*)(ws + 67108864);              // 256 KiB
    float*    wslot   = (float*)(ws + 67371008);            // 64 KiB
    float*    psum    = (float*)(ws + 67698688);            // 32 B
    int*      cnt     = (int*)(ws + 67698720);              // 32 B

    // zero cnt + psum (adjacent, 64 B) before prep_all's fused routing atomics
    hipMemsetAsync(ws + 67698688, 0, 64, stream);

    hipLaunchKernelGGL(prep_all, dim3(2560), dim3(256), 0, stream,
                       x, Wr, br, We, xb, Webt, wslot, entries, cnt, psum);
    hipLaunchKernelGGL(moe_gemm, dim3(4096), dim3(256), 0, stream,
                       xb, Webt, be, entries, cnt, wslot, yslot);
    hipLaunchKernelGGL(combine_kernel, dim3(4096), dim3(256), 0, stream,
                       yslot, psum, cnt, out);
}